// Round 4
// baseline (43.614 us; speedup 1.0000x reference)
//
#include <hip/hip_runtime.h>
#include <hip/hip_bf16.h>
#include <math.h>

#define BB 32
#define SS 256
#define DD 128
#define KK 16
#define VV 50000
#define SK (SS*KK)   // 4096

typedef __attribute__((ext_vector_type(8))) short bf16x8;
typedef __attribute__((ext_vector_type(4))) float f32x4;
typedef unsigned short ushort_t;

static __device__ __forceinline__ short f2bf(float f) {
    unsigned u = __float_as_uint(f);
    unsigned r = (u + 0x7fffu + ((u >> 16) & 1u)) >> 16;
    return (short)r;
}

// byte offset of element (row, d) in a [R][128] bf16 LDS tile, XOR-swizzled
// (16B chunk index q -> q ^ (row&7))
static __device__ __forceinline__ int lds_off(int row, int d) {
    return row * 256 + ((d * 2) ^ ((row & 7) << 4));
}

static __device__ __forceinline__ void gload_lds16(const void* g, void* lds) {
    __builtin_amdgcn_global_load_lds(
        (const __attribute__((address_space(1))) unsigned int*)g,
        (__attribute__((address_space(3))) unsigned int*)lds, 16, 0, 0);
}

// ---------------- convert kernel: fp32 -> bf16 (embed then latent) ----------
#define NEMB (VV*DD)          // 6,400,000
#define NLAT (BB*SS*DD)       // 1,048,576
#define NCHUNK ((NEMB+NLAT)/8)

__global__ __launch_bounds__(256)
void convert_kernel(const float* __restrict__ embed,
                    const float* __restrict__ latent,
                    ushort_t* __restrict__ ws_emb,
                    ushort_t* __restrict__ ws_lat)
{
    int i = blockIdx.x * 256 + threadIdx.x;
    if (i >= NCHUNK) return;
    const float* src;
    ushort_t* dst;
    if (i < NEMB / 8) {
        src = embed + (size_t)i * 8;
        dst = ws_emb + (size_t)i * 8;
    } else {
        int k = i - NEMB / 8;
        src = latent + (size_t)k * 8;
        dst = ws_lat + (size_t)k * 8;
    }
    float f[8];
    *(float4*)(f + 0) = ((const float4*)src)[0];
    *(float4*)(f + 4) = ((const float4*)src)[1];
    short o[8];
    #pragma unroll
    for (int e = 0; e < 8; ++e) o[e] = f2bf(f[e]);
    *(bf16x8*)dst = *(bf16x8*)o;
}

// ---------------- main kernel: B-tile staged once, m-loop over 4 A-tiles ----
#define MT 64
#define NT 128

__global__ __launch_bounds__(256)
void neg_loss_main(const ushort_t* __restrict__ lat_bf,   // [B,S,D] bf16
                   const int*      __restrict__ labels,   // [B,S]
                   const int*      __restrict__ samples,  // [B,S*(K-1)]
                   const ushort_t* __restrict__ emb_bf,   // [V,D] bf16
                   float* __restrict__ out)               // [B,S,S]
{
    __shared__ char ldsB[NT * 256];        // 32 KB, staged once
    __shared__ char ldsA[2][MT * 256];     // 2 x 16 KB double buffer

    const int b    = blockIdx.z;
    const int n0   = blockIdx.x * NT;
    const int tid  = threadIdx.x;
    const int wave = tid >> 6;
    const int lane = tid & 63;
    const int q    = lane & 15;
    const int sub  = lane >> 4;   // 0..3

    // ---- stage B: 128 gathered embedding rows (bf16), once per block ----
    #pragma unroll
    for (int t = 0; t < 8; ++t) {
        const int c0 = wave * 32 + t * 4;
        const int c  = c0 + sub;
        const int gc = n0 + c;
        const int j  = gc >> 4;
        const int k  = gc & 15;
        const int idx = (k < 15)
            ? samples[(size_t)b * (SS * (KK - 1)) + j * (KK - 1) + k]
            : labels[b * SS + j];
        const ushort_t* src = emb_bf + (size_t)idx * DD + ((q ^ (c & 7)) << 3);
        gload_lds16(src, ldsB + c0 * 256);
    }

    // ---- stage A[0]: first 64 latent rows ----
    #pragma unroll
    for (int t = 0; t < 4; ++t) {
        const int r0 = wave * 16 + t * 4;
        const int r  = r0 + sub;
        const ushort_t* src = lat_bf + ((size_t)(b * SS + r) * DD)
                                     + ((q ^ (r & 7)) << 3);
        gload_lds16(src, ldsA[0] + r0 * 256);
    }

    __syncthreads();

    const int lr = lane & 15;
    const int lk = (lane >> 4) * 8;

    // hoist B fragments: reused by all 4 m-tiles (16 bf16x8 = 64 VGPRs)
    bf16x8 bv[4][2];
    #pragma unroll
    for (int ks = 0; ks < 4; ++ks)
        #pragma unroll
        for (int nf = 0; nf < 2; ++nf)
            bv[ks][nf] = *(const bf16x8*)(ldsB + lds_off(wave * 32 + nf * 16 + lr, ks * 32 + lk));

    for (int mt = 0; mt < 4; ++mt) {
        const int m0  = mt * MT;
        const int cur = mt & 1;

        // prefetch A[mt+1] into alternate buffer (overlaps with compute)
        if (mt < 3) {
            #pragma unroll
            for (int t = 0; t < 4; ++t) {
                const int r0 = wave * 16 + t * 4;
                const int r  = r0 + sub;
                const ushort_t* src = lat_bf + ((size_t)(b * SS + (m0 + MT + r)) * DD)
                                             + ((q ^ (r & 7)) << 3);
                gload_lds16(src, ldsA[cur ^ 1] + r0 * 256);
            }
        }

        // ---- MFMA, swapped operands: D[row=candidate][col=latent_row] ----
        f32x4 acc[4][2] = {};
        #pragma unroll
        for (int ks = 0; ks < 4; ++ks) {
            const int d = ks * 32 + lk;
            bf16x8 a[4];
            #pragma unroll
            for (int mf = 0; mf < 4; ++mf)
                a[mf] = *(const bf16x8*)(ldsA[cur] + lds_off(mf * 16 + lr, d));
            #pragma unroll
            for (int mf = 0; mf < 4; ++mf)
                #pragma unroll
                for (int nf = 0; nf < 2; ++nf)
                    acc[mf][nf] = __builtin_amdgcn_mfma_f32_16x16x32_bf16(
                        bv[ks][nf], a[mf], acc[mf][nf], 0, 0, 0);
        }

        // ---- fused LSE epilogue (k group along sub*4+reg axis) ----
        #pragma unroll
        for (int mf = 0; mf < 4; ++mf) {
            #pragma unroll
            for (int nf = 0; nf < 2; ++nf) {
                const f32x4 v = acc[mf][nf];
                float mx = fmaxf(fmaxf(v[0], v[1]), fmaxf(v[2], v[3]));
                mx = fmaxf(mx, __shfl_xor(mx, 16));
                mx = fmaxf(mx, __shfl_xor(mx, 32));
                float e = __expf(v[0] - mx) + __expf(v[1] - mx)
                        + __expf(v[2] - mx) + __expf(v[3] - mx);
                e += __shfl_xor(e, 16);
                e += __shfl_xor(e, 32);
                float pos = __shfl(v[3], (lane & 15) | 48);   // k==15: sub=3,reg=3
                if (sub == 0) {
                    const int i  = m0 + mf * 16 + (lane & 15);
                    const int jj = (n0 >> 4) + wave * 2 + nf;
                    out[((size_t)b * SS + i) * SS + jj] = pos - mx - __logf(e);
                }
            }
        }

        __syncthreads();   // drains A[mt+1] loads (vmcnt) + protects buffers
    }
}

// ---------------- fallback (fp32 gather + in-kernel convert) ----------------
__global__ __launch_bounds__(256)
void neg_loss_fallback(const float* __restrict__ latent,
                       const int*   __restrict__ labels,
                       const int*   __restrict__ samples,
                       const float* __restrict__ embed,
                       float* __restrict__ out)
{
    __shared__ char ldsA[64 * 256];
    __shared__ char ldsB[64 * 256];

    const int b   = blockIdx.z;
    const int m0  = blockIdx.y * 64;
    const int n0  = blockIdx.x * 64;
    const int tid = threadIdx.x;

    {
        const int r  = tid >> 2;
        const int d0 = (tid & 3) * 32;
        const float* src = latent + ((size_t)b * SS + (m0 + r)) * DD + d0;
        float f[32];
        #pragma unroll
        for (int c = 0; c < 8; ++c)
            *(float4*)(f + 4 * c) = ((const float4*)src)[c];
        #pragma unroll
        for (int c = 0; c < 4; ++c) {
            short tmp[8];
            #pragma unroll
            for (int e = 0; e < 8; ++e) tmp[e] = f2bf(f[c * 8 + e]);
            *(bf16x8*)(ldsA + lds_off(r, d0 + c * 8)) = *(bf16x8*)tmp;
        }
    }
    {
        const int c   = tid >> 2;
        const int d0  = (tid & 3) * 32;
        const int col = n0 + c;
        const int j   = col >> 4;
        const int k   = col & 15;
        const int idx = (k < 15) ? samples[(size_t)b * (SS * (KK - 1)) + j * (KK - 1) + k]
                                 : labels[b * SS + j];
        const float* src = embed + (size_t)idx * DD + d0;
        float f[32];
        #pragma unroll
        for (int cc = 0; cc < 8; ++cc)
            *(float4*)(f + 4 * cc) = ((const float4*)src)[cc];
        #pragma unroll
        for (int cc = 0; cc < 4; ++cc) {
            short tmp[8];
            #pragma unroll
            for (int e = 0; e < 8; ++e) tmp[e] = f2bf(f[cc * 8 + e]);
            *(bf16x8*)(ldsB + lds_off(c, d0 + cc * 8)) = *(bf16x8*)tmp;
        }
    }
    __syncthreads();

    const int wave = tid >> 6;
    const int lane = tid & 63;
    const int wm = wave >> 1, wn = wave & 1;
    const int lr = lane & 15;
    const int lk = (lane >> 4) * 8;
    const int sub = lane >> 4;

    f32x4 acc[2][2] = {};
    #pragma unroll
    for (int ks = 0; ks < 4; ++ks) {
        const int d = ks * 32 + lk;
        bf16x8 a[2], bb2[2];
        #pragma unroll
        for (int mf = 0; mf < 2; ++mf)
            a[mf] = *(const bf16x8*)(ldsA + lds_off(wm * 32 + mf * 16 + lr, d));
        #pragma unroll
        for (int nf = 0; nf < 2; ++nf)
            bb2[nf] = *(const bf16x8*)(ldsB + lds_off(wn * 32 + nf * 16 + lr, d));
        #pragma unroll
        for (int mf = 0; mf < 2; ++mf)
            #pragma unroll
            for (int nf = 0; nf < 2; ++nf)
                acc[mf][nf] = __builtin_amdgcn_mfma_f32_16x16x32_bf16(
                    bb2[nf], a[mf], acc[mf][nf], 0, 0, 0);
    }

    #pragma unroll
    for (int mf = 0; mf < 2; ++mf) {
        #pragma unroll
        for (int nf = 0; nf < 2; ++nf) {
            const f32x4 v = acc[mf][nf];
            float mx = fmaxf(fmaxf(v[0], v[1]), fmaxf(v[2], v[3]));
            mx = fmaxf(mx, __shfl_xor(mx, 16));
            mx = fmaxf(mx, __shfl_xor(mx, 32));
            float e = __expf(v[0] - mx) + __expf(v[1] - mx)
                    + __expf(v[2] - mx) + __expf(v[3] - mx);
            e += __shfl_xor(e, 16);
            e += __shfl_xor(e, 32);
            float pos = __shfl(v[3], (lane & 15) | 48);
            if (sub == 0) {
                const int i  = m0 + wm * 32 + mf * 16 + (lane & 15);
                const int jj = (n0 >> 4) + wn * 2 + nf;
                out[((size_t)b * SS + i) * SS + jj] = pos - mx - __logf(e);
            }
        }
    }
}

extern "C" void kernel_launch(void* const* d_in, const int* in_sizes, int n_in,
                              void* d_out, int out_size, void* d_ws, size_t ws_size,
                              hipStream_t stream) {
    const float* latent  = (const float*)d_in[0];
    const int*   labels  = (const int*)d_in[1];
    const int*   samples = (const int*)d_in[2];
    const float* embed   = (const float*)d_in[3];
    float* out = (float*)d_out;

    const size_t ws_needed = (size_t)(NEMB + NLAT) * 2;
    if (ws_size >= ws_needed) {
        ushort_t* ws_emb = (ushort_t*)d_ws;
        ushort_t* ws_lat = ws_emb + NEMB;
        convert_kernel<<<(NCHUNK + 255) / 256, 256, 0, stream>>>(
            embed, latent, ws_emb, ws_lat);
        dim3 grid(SK / NT, 1, BB);
        neg_loss_main<<<grid, dim3(256), 0, stream>>>(
            ws_lat, labels, samples, ws_emb, out);
    } else {
        dim3 grid(SK / 64, SS / 64, BB);
        neg_loss_fallback<<<grid, dim3(256), 0, stream>>>(
            latent, labels, samples, embed, out);
    }
}

// Round 5
// 39.169 us; speedup vs baseline: 1.1135x; 1.1135x over previous
//
#include <hip/hip_runtime.h>
#include <hip/hip_bf16.h>
#include <math.h>

#define BB 32
#define SS 256
#define DD 128
#define KK 16
#define VV 50000
#define SK (SS*KK)   // 4096

typedef __attribute__((ext_vector_type(8))) short bf16x8;
typedef __attribute__((ext_vector_type(4))) float f32x4;
typedef __attribute__((ext_vector_type(16))) float f32x16;
typedef unsigned short ushort_t;

static __device__ __forceinline__ short f2bf(float f) {
    unsigned u = __float_as_uint(f);
    unsigned r = (u + 0x7fffu + ((u >> 16) & 1u)) >> 16;
    return (short)r;
}

// byte offset of element (row, d) in a [R][128] bf16 LDS tile, XOR-swizzled:
// 16B-chunk index c = d/8 -> c ^ (row & 15). Row stride 256B, 16 chunks/row.
// Read pattern (32 lanes, rows 0..31, same c): 16 distinct chunks x 2 rows
// -> 2 lanes/bank = free (m136). Must match the staging source pre-swizzle.
static __device__ __forceinline__ int lds_off(int row, int d) {
    return row * 256 + ((d * 2) ^ ((row & 15) << 4));
}

static __device__ __forceinline__ void gload_lds16(const void* g, void* lds) {
    __builtin_amdgcn_global_load_lds(
        (const __attribute__((address_space(1))) unsigned int*)g,
        (__attribute__((address_space(3))) unsigned int*)lds, 16, 0, 0);
}

// ---------------- convert kernel: fp32 -> bf16 (embed then latent) ----------
#define NEMB (VV*DD)          // 6,400,000
#define NLAT (BB*SS*DD)       // 1,048,576
#define NCHUNK ((NEMB+NLAT)/8)

__global__ __launch_bounds__(256)
void convert_kernel(const float* __restrict__ embed,
                    const float* __restrict__ latent,
                    ushort_t* __restrict__ ws_emb,
                    ushort_t* __restrict__ ws_lat)
{
    int i = blockIdx.x * 256 + threadIdx.x;
    if (i >= NCHUNK) return;
    const float* src;
    ushort_t* dst;
    if (i < NEMB / 8) {
        src = embed + (size_t)i * 8;
        dst = ws_emb + (size_t)i * 8;
    } else {
        int k = i - NEMB / 8;
        src = latent + (size_t)k * 8;
        dst = ws_lat + (size_t)k * 8;
    }
    float f[8];
    *(float4*)(f + 0) = ((const float4*)src)[0];
    *(float4*)(f + 4) = ((const float4*)src)[1];
    short o[8];
    #pragma unroll
    for (int e = 0; e < 8; ++e) o[e] = f2bf(f[e]);
    *(bf16x8*)dst = *(bf16x8*)o;
}

// ---------------- main kernel: 128 cand x 64 lat tile, 32x32x16 MFMA --------
#define MT 64     // latent rows per block
#define NT 128    // candidate rows per block

__global__ __launch_bounds__(256, 3)
void neg_loss_main(const ushort_t* __restrict__ lat_bf,   // [B,S,D] bf16
                   const int*      __restrict__ labels,   // [B,S]
                   const int*      __restrict__ samples,  // [B,S*(K-1)]
                   const ushort_t* __restrict__ emb_bf,   // [V,D] bf16
                   float* __restrict__ out)               // [B,S,S]
{
    __shared__ char ldsB[NT * 256];   // 32 KB candidates
    __shared__ char ldsA[MT * 256];   // 16 KB latent

    const int b    = blockIdx.z;
    const int m0   = blockIdx.y * MT;
    const int n0   = blockIdx.x * NT;
    const int tid  = threadIdx.x;
    const int wave = tid >> 6;
    const int lane = tid & 63;
    const int q    = lane & 15;
    const int sub  = lane >> 4;   // 0..3

    // ---- stage B: 128 gathered embedding rows, src pre-swizzled ----
    #pragma unroll
    for (int t = 0; t < 8; ++t) {
        const int c0 = wave * 32 + t * 4;
        const int c  = c0 + sub;
        const int gc = n0 + c;
        const int j  = gc >> 4;
        const int k  = gc & 15;
        const int idx = (k < 15)
            ? samples[(size_t)b * (SS * (KK - 1)) + j * (KK - 1) + k]
            : labels[b * SS + j];
        const ushort_t* src = emb_bf + (size_t)idx * DD + ((q ^ (c & 15)) << 3);
        gload_lds16(src, ldsB + c0 * 256);
    }

    // ---- stage A: 64 latent rows ----
    #pragma unroll
    for (int t = 0; t < 4; ++t) {
        const int r0 = wave * 16 + t * 4;
        const int r  = r0 + sub;
        const ushort_t* src = lat_bf + ((size_t)(b * SS + m0 + r) * DD)
                                     + ((q ^ (r & 15)) << 3);
        gload_lds16(src, ldsA + r0 * 256);
    }

    __syncthreads();

    // ---- MFMA 32x32x16, swapped: D[row=cand][col=lat] ----
    // wave handles cand rows [wave*32, wave*32+32) x all 64 lat rows.
    // A frag: row = lane&31 (cand), k = (lane>>5)*8 + e
    // B frag: col = lane&31 (lat),  k = (lane>>5)*8 + e
    const int l31 = lane & 31;
    const int hi  = lane >> 5;
    const int rB  = wave * 32 + l31;   // cand row in tile

    f32x16 acc0 = {}, acc1 = {};
    #pragma unroll
    for (int ks = 0; ks < 8; ++ks) {
        const int d = ks * 16 + hi * 8;
        bf16x8 av  = *(const bf16x8*)(ldsB + lds_off(rB, d));
        bf16x8 bv0 = *(const bf16x8*)(ldsA + lds_off(l31, d));
        bf16x8 bv1 = *(const bf16x8*)(ldsA + lds_off(32 + l31, d));
        acc0 = __builtin_amdgcn_mfma_f32_32x32x16_bf16(av, bv0, acc0, 0, 0, 0);
        acc1 = __builtin_amdgcn_mfma_f32_32x32x16_bf16(av, bv1, acc1, 0, 0, 0);
    }

    // ---- fused LSE epilogue ----
    // D rows per lane: (reg&3) + 8*(reg>>2) + 4*hi. k-group 0 (cand rows 0-15)
    // = regs 0-7 (both hi halves); group 1 (rows 16-31) = regs 8-15.
    // Row 15 = hi=1 reg 7; row 31 = hi=1 reg 15.
    const int jb = (n0 >> 4) + wave * 2;
    #pragma unroll
    for (int f = 0; f < 2; ++f) {
        const f32x16 v = f ? acc1 : acc0;
        float pm0 = fmaxf(fmaxf(fmaxf(v[0], v[1]), fmaxf(v[2], v[3])),
                          fmaxf(fmaxf(v[4], v[5]), fmaxf(v[6], v[7])));
        float pm1 = fmaxf(fmaxf(fmaxf(v[8], v[9]), fmaxf(v[10], v[11])),
                          fmaxf(fmaxf(v[12], v[13]), fmaxf(v[14], v[15])));
        float om0 = fmaxf(pm0, __shfl_xor(pm0, 32));
        float om1 = fmaxf(pm1, __shfl_xor(pm1, 32));
        float ps0 = __expf(v[0] - om0) + __expf(v[1] - om0)
                  + __expf(v[2] - om0) + __expf(v[3] - om0)
                  + __expf(v[4] - om0) + __expf(v[5] - om0)
                  + __expf(v[6] - om0) + __expf(v[7] - om0);
        float ps1 = __expf(v[8]  - om1) + __expf(v[9]  - om1)
                  + __expf(v[10] - om1) + __expf(v[11] - om1)
                  + __expf(v[12] - om1) + __expf(v[13] - om1)
                  + __expf(v[14] - om1) + __expf(v[15] - om1);
        float s0 = ps0 + __shfl_xor(ps0, 32);
        float s1 = ps1 + __shfl_xor(ps1, 32);
        float pos0 = __shfl_xor(v[7], 32);   // hi=0 lanes receive row 15
        float pos1 = v[15];                  // hi=1 lanes hold row 31 in-lane
        const float pos = hi ? pos1 : pos0;
        const float om  = hi ? om1  : om0;
        const float s   = hi ? s1   : s0;
        const int i = m0 + f * 32 + l31;
        out[((size_t)b * SS + i) * SS + (jb + hi)] = pos - om - __logf(s);
    }
}

// ---------------- fallback (fp32 gather + in-kernel convert) ----------------
__global__ __launch_bounds__(256)
void neg_loss_fallback(const float* __restrict__ latent,
                       const int*   __restrict__ labels,
                       const int*   __restrict__ samples,
                       const float* __restrict__ embed,
                       float* __restrict__ out)
{
    __shared__ char ldsA[64 * 256];
    __shared__ char ldsB[64 * 256];

    const int b   = blockIdx.z;
    const int m0  = blockIdx.y * 64;
    const int n0  = blockIdx.x * 64;
    const int tid = threadIdx.x;

    {
        const int r  = tid >> 2;
        const int d0 = (tid & 3) * 32;
        const float* src = latent + ((size_t)b * SS + (m0 + r)) * DD + d0;
        float f[32];
        #pragma unroll
        for (int c = 0; c < 8; ++c)
            *(float4*)(f + 4 * c) = ((const float4*)src)[c];
        #pragma unroll
        for (int c = 0; c < 4; ++c) {
            short tmp[8];
            #pragma unroll
            for (int e = 0; e < 8; ++e) tmp[e] = f2bf(f[c * 8 + e]);
            *(bf16x8*)(ldsA + lds_off(r, d0 + c * 8)) = *(bf16x8*)tmp;
        }
    }
    {
        const int c   = tid >> 2;
        const int d0  = (tid & 3) * 32;
        const int col = n0 + c;
        const int j   = col >> 4;
        const int k   = col & 15;
        const int idx = (k < 15) ? samples[(size_t)b * (SS * (KK - 1)) + j * (KK - 1) + k]
                                 : labels[b * SS + j];
        const float* src = embed + (size_t)idx * DD + d0;
        float f[32];
        #pragma unroll
        for (int cc = 0; cc < 8; ++cc)
            *(float4*)(f + 4 * cc) = ((const float4*)src)[cc];
        #pragma unroll
        for (int cc = 0; cc < 4; ++cc) {
            short tmp[8];
            #pragma unroll
            for (int e = 0; e < 8; ++e) tmp[e] = f2bf(f[cc * 8 + e]);
            *(bf16x8*)(ldsB + lds_off(c, d0 + cc * 8)) = *(bf16x8*)tmp;
        }
    }
    __syncthreads();

    const int wave = tid >> 6;
    const int lane = tid & 63;
    const int wm = wave >> 1, wn = wave & 1;
    const int lr = lane & 15;
    const int lk = (lane >> 4) * 8;
    const int sub = lane >> 4;

    f32x4 acc[2][2] = {};
    #pragma unroll
    for (int ks = 0; ks < 4; ++ks) {
        const int d = ks * 32 + lk;
        bf16x8 a[2], bb2[2];
        #pragma unroll
        for (int mf = 0; mf < 2; ++mf)
            a[mf] = *(const bf16x8*)(ldsA + lds_off(wm * 32 + mf * 16 + lr, d));
        #pragma unroll
        for (int nf = 0; nf < 2; ++nf)
            bb2[nf] = *(const bf16x8*)(ldsB + lds_off(wn * 32 + nf * 16 + lr, d));
        #pragma unroll
        for (int mf = 0; mf < 2; ++mf)
            #pragma unroll
            for (int nf = 0; nf < 2; ++nf)
                acc[mf][nf] = __builtin_amdgcn_mfma_f32_16x16x32_bf16(
                    bb2[nf], a[mf], acc[mf][nf], 0, 0, 0);
    }

    #pragma unroll
    for (int mf = 0; mf < 2; ++mf) {
        #pragma unroll
        for (int nf = 0; nf < 2; ++nf) {
            const f32x4 v = acc[mf][nf];
            float mx = fmaxf(fmaxf(v[0], v[1]), fmaxf(v[2], v[3]));
            mx = fmaxf(mx, __shfl_xor(mx, 16));
            mx = fmaxf(mx, __shfl_xor(mx, 32));
            float e = __expf(v[0] - mx) + __expf(v[1] - mx)
                    + __expf(v[2] - mx) + __expf(v[3] - mx);
            e += __shfl_xor(e, 16);
            e += __shfl_xor(e, 32);
            float pos = __shfl(v[3], (lane & 15) | 48);
            if (sub == 0) {
                const int i  = m0 + wm * 32 + mf * 16 + (lane & 15);
                const int jj = (n0 >> 4) + wn * 2 + nf;
                out[((size_t)b * SS + i) * SS + jj] = pos - mx - __logf(e);
            }
        }
    }
}

extern "C" void kernel_launch(void* const* d_in, const int* in_sizes, int n_in,
                              void* d_out, int out_size, void* d_ws, size_t ws_size,
                              hipStream_t stream) {
    const float* latent  = (const float*)d_in[0];
    const int*   labels  = (const int*)d_in[1];
    const int*   samples = (const int*)d_in[2];
    const float* embed   = (const float*)d_in[3];
    float* out = (float*)d_out;

    const size_t ws_needed = (size_t)(NEMB + NLAT) * 2;
    if (ws_size >= ws_needed) {
        ushort_t* ws_emb = (ushort_t*)d_ws;
        ushort_t* ws_lat = ws_emb + NEMB;
        convert_kernel<<<(NCHUNK + 255) / 256, 256, 0, stream>>>(
            embed, latent, ws_emb, ws_lat);
        dim3 grid(SK / NT, SS / MT, BB);
        neg_loss_main<<<grid, dim3(256), 0, stream>>>(
            ws_lat, labels, samples, ws_emb, out);
    } else {
        dim3 grid(SK / 64, SS / 64, BB);
        neg_loss_fallback<<<grid, dim3(256), 0, stream>>>(
            latent, labels, samples, embed, out);
    }
}

// Round 6
// 35.618 us; speedup vs baseline: 1.2245x; 1.0997x over previous
//
#include <hip/hip_runtime.h>
#include <hip/hip_bf16.h>
#include <math.h>

#define BB 32
#define SS 256
#define DD 128
#define KK 16
#define VV 50000
#define SK (SS*KK)   // 4096

typedef __attribute__((ext_vector_type(8))) short bf16x8;
typedef __attribute__((ext_vector_type(4))) float f32x4;
typedef __attribute__((ext_vector_type(16))) float f32x16;
typedef unsigned short ushort_t;

static __device__ __forceinline__ short f2bf(float f) {
    unsigned u = __float_as_uint(f);
    unsigned r = (u + 0x7fffu + ((u >> 16) & 1u)) >> 16;
    return (short)r;
}

// byte offset of element (row, d) in a [R][128] bf16 LDS tile, XOR-swizzled:
// 16B-chunk index c = d/8 -> c ^ (row & 15). 2 lanes/bank on frag reads = free.
static __device__ __forceinline__ int lds_off(int row, int d) {
    return row * 256 + ((d * 2) ^ ((row & 15) << 4));
}

static __device__ __forceinline__ void gload_lds16(const void* g, void* lds) {
    __builtin_amdgcn_global_load_lds(
        (const __attribute__((address_space(1))) unsigned int*)g,
        (__attribute__((address_space(3))) unsigned int*)lds, 16, 0, 0);
}

// ---------------- convert kernel: latent only, fp32 -> bf16 -----------------
#define NLAT (BB*SS*DD)       // 1,048,576
#define NCHUNK_LAT (NLAT/8)   // 131,072

__global__ __launch_bounds__(256)
void convert_lat_kernel(const float* __restrict__ latent,
                        ushort_t* __restrict__ ws_lat)
{
    int i = blockIdx.x * 256 + threadIdx.x;
    if (i >= NCHUNK_LAT) return;
    const float* src = latent + (size_t)i * 8;
    float f[8];
    *(float4*)(f + 0) = ((const float4*)src)[0];
    *(float4*)(f + 4) = ((const float4*)src)[1];
    short o[8];
    #pragma unroll
    for (int e = 0; e < 8; ++e) o[e] = f2bf(f[e]);
    *(bf16x8*)(ws_lat + (size_t)i * 8) = *(bf16x8*)o;
}

// ---------------- main kernel ------------------------------------------------
// grid (32 n-tiles, 1, 32 batches). Block = 4 waves.
// Per wave: 32 candidate rows (B) gathered fp32->bf16 into REGISTERS (av[8]).
// A (latent) staged bf16 via global_load_lds, 64-row tiles, double-buffered.
// m-loop over 4 latent tiles; 1 barrier per tile.
#define MT 64
#define NT 128

__global__ __launch_bounds__(256)
void neg_loss_main(const ushort_t* __restrict__ lat_bf,   // [B,S,D] bf16 (ws)
                   const int*      __restrict__ labels,   // [B,S]
                   const int*      __restrict__ samples,  // [B,S*(K-1)]
                   const float*    __restrict__ embed,    // [V,D] fp32
                   float* __restrict__ out)               // [B,S,S]
{
    __shared__ char ldsA[2][MT * 256];   // 2 x 16 KB

    const int b    = blockIdx.z;
    const int n0   = blockIdx.x * NT;
    const int tid  = threadIdx.x;
    const int wave = tid >> 6;
    const int lane = tid & 63;
    const int q    = lane & 15;
    const int sub  = lane >> 4;
    const int l31  = lane & 31;
    const int hi   = lane >> 5;

    // ---- candidate index for this lane's B row ----
    const int rB  = wave * 32 + l31;     // cand row in tile, 0..127
    const int gc  = n0 + rB;             // global candidate 0..4095
    const int j   = gc >> 4;
    const int k   = gc & 15;
    const int idx = (k < 15)
        ? samples[(size_t)b * (SS * (KK - 1)) + j * (KK - 1) + k]
        : labels[b * SS + j];

    // ---- stage A[0] (latent rows 0..63) early, async ----
    #pragma unroll
    for (int t = 0; t < 4; ++t) {
        const int r0 = wave * 16 + t * 4;
        const int r  = r0 + sub;
        const ushort_t* src = lat_bf + ((size_t)(b * SS + r) * DD)
                                     + ((q ^ (r & 15)) << 3);
        gload_lds16(src, ldsA[0] + r0 * 256);
    }

    // ---- B gather: this lane's half-row (k = ks*16 + hi*8 + e), fp32 ----
    const float* rowp = embed + (size_t)idx * DD + hi * 8;
    f32x4 fb[16];
    #pragma unroll
    for (int ks = 0; ks < 8; ++ks) {
        fb[2 * ks]     = *(const f32x4*)(rowp + ks * 16);
        fb[2 * ks + 1] = *(const f32x4*)(rowp + ks * 16 + 4);
    }
    bf16x8 av[8];
    #pragma unroll
    for (int ks = 0; ks < 8; ++ks) {
        short t8[8];
        #pragma unroll
        for (int e = 0; e < 4; ++e) t8[e]     = f2bf(fb[2 * ks][e]);
        #pragma unroll
        for (int e = 0; e < 4; ++e) t8[4 + e] = f2bf(fb[2 * ks + 1][e]);
        av[ks] = *(bf16x8*)t8;
    }

    __syncthreads();   // A[0] ready (drains vmcnt before barrier)

    const int jb = (n0 >> 4) + wave * 2;

    for (int mt = 0; mt < 4; ++mt) {
        const int cur = mt & 1;

        // prefetch A[mt+1] into alternate buffer (stays in flight over MFMA)
        if (mt < 3) {
            #pragma unroll
            for (int t = 0; t < 4; ++t) {
                const int r0 = wave * 16 + t * 4;
                const int r  = r0 + sub;
                const ushort_t* src = lat_bf
                    + ((size_t)(b * SS + ((mt + 1) * MT + r)) * DD)
                    + ((q ^ (r & 15)) << 3);
                gload_lds16(src, ldsA[cur ^ 1] + r0 * 256);
            }
        }

        // ---- MFMA 32x32x16, swapped: D[row=cand][col=lat] ----
        f32x16 acc0 = {}, acc1 = {};
        #pragma unroll
        for (int ks = 0; ks < 8; ++ks) {
            const int d = ks * 16 + hi * 8;
            bf16x8 bv0 = *(const bf16x8*)(ldsA[cur] + lds_off(l31, d));
            bf16x8 bv1 = *(const bf16x8*)(ldsA[cur] + lds_off(32 + l31, d));
            acc0 = __builtin_amdgcn_mfma_f32_32x32x16_bf16(av[ks], bv0, acc0, 0, 0, 0);
            acc1 = __builtin_amdgcn_mfma_f32_32x32x16_bf16(av[ks], bv1, acc1, 0, 0, 0);
        }

        // ---- fused LSE epilogue ----
        // D rows/lane: (reg&3)+8*(reg>>2)+4*hi. group0 = regs0-7, group1 = 8-15.
        #pragma unroll
        for (int f = 0; f < 2; ++f) {
            const f32x16 v = f ? acc1 : acc0;
            float pm0 = fmaxf(fmaxf(fmaxf(v[0], v[1]), fmaxf(v[2], v[3])),
                              fmaxf(fmaxf(v[4], v[5]), fmaxf(v[6], v[7])));
            float pm1 = fmaxf(fmaxf(fmaxf(v[8], v[9]), fmaxf(v[10], v[11])),
                              fmaxf(fmaxf(v[12], v[13]), fmaxf(v[14], v[15])));
            float om0 = fmaxf(pm0, __shfl_xor(pm0, 32));
            float om1 = fmaxf(pm1, __shfl_xor(pm1, 32));
            float ps0 = __expf(v[0] - om0) + __expf(v[1] - om0)
                      + __expf(v[2] - om0) + __expf(v[3] - om0)
                      + __expf(v[4] - om0) + __expf(v[5] - om0)
                      + __expf(v[6] - om0) + __expf(v[7] - om0);
            float ps1 = __expf(v[8]  - om1) + __expf(v[9]  - om1)
                      + __expf(v[10] - om1) + __expf(v[11] - om1)
                      + __expf(v[12] - om1) + __expf(v[13] - om1)
                      + __expf(v[14] - om1) + __expf(v[15] - om1);
            float s0 = ps0 + __shfl_xor(ps0, 32);
            float s1 = ps1 + __shfl_xor(ps1, 32);
            float pos0 = __shfl_xor(v[7], 32);  // hi=0 lanes get row 15
            float pos1 = v[15];                 // hi=1 lanes hold row 31
            const float pos = hi ? pos1 : pos0;
            const float om  = hi ? om1  : om0;
            const float s   = hi ? s1   : s0;
            const int i = mt * MT + f * 32 + l31;
            out[((size_t)b * SS + i) * SS + (jb + hi)] = pos - om - __logf(s);
        }

        __syncthreads();   // A[mt+1] staged + all reads of A[cur] done
    }
}

// ---------------- fallback (fp32 gather + in-kernel convert) ----------------
__global__ __launch_bounds__(256)
void neg_loss_fallback(const float* __restrict__ latent,
                       const int*   __restrict__ labels,
                       const int*   __restrict__ samples,
                       const float* __restrict__ embed,
                       float* __restrict__ out)
{
    __shared__ char ldsA[64 * 256];
    __shared__ char ldsB[64 * 256];

    const int b   = blockIdx.z;
    const int m0  = blockIdx.y * 64;
    const int n0  = blockIdx.x * 64;
    const int tid = threadIdx.x;

    {
        const int r  = tid >> 2;
        const int d0 = (tid & 3) * 32;
        const float* src = latent + ((size_t)b * SS + (m0 + r)) * DD + d0;
        float f[32];
        #pragma unroll
        for (int c = 0; c < 8; ++c)
            *(float4*)(f + 4 * c) = ((const float4*)src)[c];
        #pragma unroll
        for (int c = 0; c < 4; ++c) {
            short tmp[8];
            #pragma unroll
            for (int e = 0; e < 8; ++e) tmp[e] = f2bf(f[c * 8 + e]);
            *(bf16x8*)(ldsA + lds_off(r, d0 + c * 8)) = *(bf16x8*)tmp;
        }
    }
    {
        const int c   = tid >> 2;
        const int d0  = (tid & 3) * 32;
        const int col = n0 + c;
        const int j   = col >> 4;
        const int k   = col & 15;
        const int idx = (k < 15) ? samples[(size_t)b * (SS * (KK - 1)) + j * (KK - 1) + k]
                                 : labels[b * SS + j];
        const float* src = embed + (size_t)idx * DD + d0;
        float f[32];
        #pragma unroll
        for (int cc = 0; cc < 8; ++cc)
            *(float4*)(f + 4 * cc) = ((const float4*)src)[cc];
        #pragma unroll
        for (int cc = 0; cc < 4; ++cc) {
            short tmp[8];
            #pragma unroll
            for (int e = 0; e < 8; ++e) tmp[e] = f2bf(f[cc * 8 + e]);
            *(bf16x8*)(ldsB + lds_off(c, d0 + cc * 8)) = *(bf16x8*)tmp;
        }
    }
    __syncthreads();

    const int wave = tid >> 6;
    const int lane = tid & 63;
    const int wm = wave >> 1, wn = wave & 1;
    const int lr = lane & 15;
    const int lk = (lane >> 4) * 8;
    const int sub = lane >> 4;

    f32x4 acc[2][2] = {};
    #pragma unroll
    for (int ks = 0; ks < 4; ++ks) {
        const int d = ks * 32 + lk;
        bf16x8 a[2], bb2[2];
        #pragma unroll
        for (int mf = 0; mf < 2; ++mf)
            a[mf] = *(const bf16x8*)(ldsA + lds_off(wm * 32 + mf * 16 + lr, d));
        #pragma unroll
        for (int nf = 0; nf < 2; ++nf)
            bb2[nf] = *(const bf16x8*)(ldsB + lds_off(wn * 32 + nf * 16 + lr, d));
        #pragma unroll
        for (int mf = 0; mf < 2; ++mf)
            #pragma unroll
            for (int nf = 0; nf < 2; ++nf)
                acc[mf][nf] = __builtin_amdgcn_mfma_f32_16x16x32_bf16(
                    bb2[nf], a[mf], acc[mf][nf], 0, 0, 0);
    }

    #pragma unroll
    for (int mf = 0; mf < 2; ++mf) {
        #pragma unroll
        for (int nf = 0; nf < 2; ++nf) {
            const f32x4 v = acc[mf][nf];
            float mx = fmaxf(fmaxf(v[0], v[1]), fmaxf(v[2], v[3]));
            mx = fmaxf(mx, __shfl_xor(mx, 16));
            mx = fmaxf(mx, __shfl_xor(mx, 32));
            float e = __expf(v[0] - mx) + __expf(v[1] - mx)
                    + __expf(v[2] - mx) + __expf(v[3] - mx);
            e += __shfl_xor(e, 16);
            e += __shfl_xor(e, 32);
            float pos = __shfl(v[3], (lane & 15) | 48);
            if (sub == 0) {
                const int i  = m0 + wm * 32 + mf * 16 + (lane & 15);
                const int jj = (n0 >> 4) + wn * 2 + nf;
                out[((size_t)b * SS + i) * SS + jj] = pos - mx - __logf(e);
            }
        }
    }
}

extern "C" void kernel_launch(void* const* d_in, const int* in_sizes, int n_in,
                              void* d_out, int out_size, void* d_ws, size_t ws_size,
                              hipStream_t stream) {
    const float* latent  = (const float*)d_in[0];
    const int*   labels  = (const int*)d_in[1];
    const int*   samples = (const int*)d_in[2];
    const float* embed   = (const float*)d_in[3];
    float* out = (float*)d_out;

    const size_t ws_needed = (size_t)NLAT * 2;
    if (ws_size >= ws_needed) {
        ushort_t* ws_lat = (ushort_t*)d_ws;
        convert_lat_kernel<<<(NCHUNK_LAT + 255) / 256, 256, 0, stream>>>(
            latent, ws_lat);
        dim3 grid(SK / NT, 1, BB);
        neg_loss_main<<<grid, dim3(256), 0, stream>>>(
            ws_lat, labels, samples, embed, out);
    } else {
        dim3 grid(SK / 64, SS / 64, BB);
        neg_loss_fallback<<<grid, dim3(256), 0, stream>>>(
            latent, labels, samples, embed, out);
    }
}